// Round 1
// baseline (742.436 us; speedup 1.0000x reference)
//
#include <hip/hip_runtime.h>

// SimpleARRNN: GRU encoder (len<=512) + AR decoder (257 outputs). B=512, I=64, H=100, O=64. fp32.
// Fused affine input paths: W_c = W_ih@W_embed [300x64], b_c = W_ih@b_embed + b_ih
//                           W_d = W_c@W_proj   [300x100], b_d = W_c@b_proj + b_c
// rnn9 (R9): staggered two-phase pipeline. 2 elements/block (long+short, length-sorted),
// 256 blocks x 512 threads, waves_per_eu(2,2).
// R8 structure kept: 4-lane row split (l=tid&3 owns h-cols 25l..25l+24, ctx-cols 16l..16l+15),
// register-resident weights (6 passes), DPP quad_perm xor1+xor2 reduce, slot = 128p + g.
// R9 change: per step, phase A = dots(e0,t) || gate(e1,t-1) || out(e1,t-1);
//            phase B = dots(e1,t) || gate(e0,t) || out(e0,t). Gate/out hide under the
//            opposite element's dots instead of occupying their own barrier phase
//            (R8 gate phase left 312/512 lanes idle and its LDS-turnaround +
//            transcendental chain fully exposed, 2x per step). Same 2 barriers/step.
// sctx double-buffered per element: prefetch writes buf (t+1)&1 while dots read buf t&1.
// h in LDS: 4 chunks of 25 at stride 28 (banks 0/28/24/20 per beat - disjoint).

#define B_  512
#define LC_ 512
#define I_  64
#define H_  100
#define O_  64
#define T_  256
#define H3  300

// ws float offsets
#define WS_WC   0        // [300][64]
#define WS_BC   19200    // [300]
#define WS_WD   19500    // [300][100]
#define WS_BD   49500    // [300]
#define WS_PERM 49800    // int[512]

typedef float v2f __attribute__((ext_vector_type(2)));

__global__ __launch_bounds__(64) void prep1(const float* __restrict__ Wih,
                                            const float* __restrict__ bih,
                                            const float* __restrict__ Wemb,
                                            const float* __restrict__ bemb,
                                            float* __restrict__ ws) {
    int j = blockIdx.x;   // 0..299
    int i = threadIdx.x;  // 0..63
    float acc = 0.f;
    for (int k = 0; k < H_; ++k) acc += Wih[j * H_ + k] * Wemb[k * I_ + i];
    ws[WS_WC + j * I_ + i] = acc;
    if (i == 0) {
        float b = bih[j];
        for (int k = 0; k < H_; ++k) b += Wih[j * H_ + k] * bemb[k];
        ws[WS_BC + j] = b;
    }
}

__global__ __launch_bounds__(128) void prep2(const float* __restrict__ Wproj,
                                             const float* __restrict__ bproj,
                                             float* __restrict__ ws) {
    int j = blockIdx.x;   // 0..299
    int u = threadIdx.x;
    const float* Wc = ws + WS_WC;
    if (u < H_) {
        float acc = 0.f;
        for (int o = 0; o < O_; ++o) acc += Wc[j * I_ + o] * Wproj[o * H_ + u];
        ws[WS_WD + j * H_ + u] = acc;
    }
    if (u == 0) {
        float b = ws[WS_BC + j];
        for (int o = 0; o < O_; ++o) b += Wc[j * I_ + o] * bproj[o];
        ws[WS_BD + j] = b;
    }
}

// rank elements by length descending -> perm (longest first)
__global__ __launch_bounds__(512) void sortk(const int* __restrict__ lens,
                                             int* __restrict__ perm) {
    __shared__ int sl[B_];
    int tid = threadIdx.x;
    sl[tid] = lens[tid];
    __syncthreads();
    int li = sl[tid];
    int rank = 0;
    for (int j = 0; j < B_; ++j) {
        int lj = sl[j];
        rank += (lj > li) || (lj == li && j < tid);
    }
    perm[rank] = tid;
}

__device__ __forceinline__ float sigm_(float x) { return 1.f / (1.f + __expf(-x)); }
__device__ __forceinline__ float tanh_(float x) {
    float t = __expf(-2.f * fabsf(x));
    float r = (1.f - t) / (1.f + t);
    return (x >= 0.f) ? r : -r;
}

template <int CTRL>
__device__ __forceinline__ float dppmov_(float x) {
    return __int_as_float(
        __builtin_amdgcn_mov_dpp(__float_as_int(x), CTRL, 0xF, 0xF, true));
}
// reduce across the 4 lanes of a quad (row group); all 4 lanes end with the sum
__device__ __forceinline__ float red4_(float a) {
    a += dppmov_<0xB1>(a);    // quad_perm [1,0,3,2] = xor1 (involution, verified R5/R7)
    a += dppmov_<0x4E>(a);    // quad_perm [2,3,0,1] = xor2
    return a;
}

// h-row dot: 12 v2f pairs + tail scalar (25 cols), then quad reduce
__device__ __forceinline__ float dotH_(const v2f* __restrict__ w2, float w1,
                                       const v2f* __restrict__ hv2, float h24) {
    v2f a = {0.f, 0.f};
    #pragma unroll
    for (int j = 0; j < 12; ++j) a = w2[j] * hv2[j] + a;   // v_pk_fma_f32
    return red4_(fmaf(w1, h24, a.x + a.y));
}
// ctx-row dot: 8 v2f pairs (16 cols), then quad reduce
__device__ __forceinline__ float dotC_(const v2f* __restrict__ w2,
                                       const v2f* __restrict__ cv2) {
    v2f a = {0.f, 0.f};
    #pragma unroll
    for (int j = 0; j < 8; ++j) a = w2[j] * cv2[j] + a;
    return red4_(a.x + a.y);
}

__global__ __attribute__((amdgpu_flat_work_group_size(512, 512)))
__attribute__((amdgpu_waves_per_eu(2, 2)))
void rnn9(const float* __restrict__ ctx, const int* __restrict__ lens,
          const float* __restrict__ Whh, const float* __restrict__ bhh,
          const float* __restrict__ Wproj, const float* __restrict__ bproj,
          const float* __restrict__ ws, float* __restrict__ out) {

    const int tid = threadIdx.x;
    const int l   = tid & 3;          // quad lane: h-cols 25l.., ctx-cols 16l..
    const int g   = tid >> 2;         // 0..127 row-group
    const bool wl = (l == 0);

    const int* perm = (const int*)(ws + WS_PERM);
    const int e0 = perm[blockIdx.x];         // long element
    const int e1 = perm[511 - blockIdx.x];   // short element
    const int len0 = lens[e0], len1 = lens[e1];

    __shared__ __align__(16) float sh[2][112];      // h: 4 chunks of 25, stride 28
    __shared__ __align__(16) float sctx[2][2][64];  // [elem][buf][64], double-buffered
    __shared__ float sdot[2][672];                  // gh 0..299 | xi 300..599 | proj 600..663
    __shared__ float sbh[H3], sbx[H3];

    // ---- per-pass config: slot = 128p + g (R8 mapping, unchanged) ----
    const bool p2hh = (g < 44);      // pass2: slot 256..299 -> Whh, else input-path row g-44
    const bool p4a  = (g < 88);      // pass4 enc: Wc row 212+g; dec: Wd row 212+g (else Wproj)
    const bool p5a  = (g < 24);      // pass5 dec only: Wproj row 40+g

    // ---- register-resident weights: 6 passes x (12 v2f + tail) ----
    v2f   w2[6][12];
    float w1[6];
    {
        const float* r0 = Whh + g * H_ + 25 * l;
        const float* r1 = Whh + (128 + g) * H_ + 25 * l;
        #pragma unroll
        for (int j = 0; j < 12; ++j) {
            w2[0][j] = v2f{r0[2 * j], r0[2 * j + 1]};
            w2[1][j] = v2f{r1[2 * j], r1[2 * j + 1]};
        }
        w1[0] = r0[24]; w1[1] = r1[24];
        if (p2hh) {
            const float* r2 = Whh + (256 + g) * H_ + 25 * l;
            #pragma unroll
            for (int j = 0; j < 12; ++j) w2[2][j] = v2f{r2[2 * j], r2[2 * j + 1]};
            w1[2] = r2[24];
        } else {
            const float* r2 = ws + WS_WC + (g - 44) * I_ + 16 * l;
            #pragma unroll
            for (int j = 0; j < 8; ++j) w2[2][j] = v2f{r2[2 * j], r2[2 * j + 1]};
        }
        const float* r3 = ws + WS_WC + (84 + g) * I_ + 16 * l;
        #pragma unroll
        for (int j = 0; j < 8; ++j) w2[3][j] = v2f{r3[2 * j], r3[2 * j + 1]};
        if (p4a) {
            const float* r4 = ws + WS_WC + (212 + g) * I_ + 16 * l;
            #pragma unroll
            for (int j = 0; j < 8; ++j) w2[4][j] = v2f{r4[2 * j], r4[2 * j + 1]};
        }
    }

    // ---- roles (R8 assignments; per-phase element flip) ----
    const int ge = (tid >= 100);                 // gate threads tid<200: tid<100 -> e0 (phase B),
    const int gi = tid - (ge ? 100 : 0);         //                       100..199 -> e1 (phase A)
    const int hs = 28 * (gi / 25) + (gi % 25);   // h slot in 28-stride chunks
    float hreg = 0.f;

    const bool iso = (tid >= 256 && tid < 320);  // out threads: 64 lanes, one element per phase
    const int oo = tid & 63;
    float* oute0 = out + (size_t)e0 * (T_ + 1) * O_;
    float* oute1 = out + (size_t)e1 * (T_ + 1) * O_;
    float bpr = 0.f;
    if (iso) bpr = bproj[oo];

    const bool isp = (tid >= 384 && tid < 400);  // prefetch: 16 lanes, one element per phase
    const int pi = tid & 15;
    const float4* pctx0 = (const float4*)(ctx + (size_t)e0 * LC_ * I_);
    const float4* pctx1 = (const float4*)(ctx + (size_t)e1 * LC_ * I_);

    // ---- init ----
    if (tid < 224) ((float*)sh)[tid] = 0.f;
    if (tid < H3) { sbh[tid] = bhh[tid]; sbx[tid] = (ws + WS_BC)[tid]; }
    if (isp) {
        *(float4*)&sctx[0][0][4 * pi] = pctx0[pi];   // e0, t=0
        *(float4*)&sctx[1][0][4 * pi] = pctx1[pi];   // e1, t=0
    }
    __syncthreads();

    // ---- helpers ----
    auto gate_ = [&](int e) {
        const float* sd = sdot[e];
        float gr = sd[gi]       + sbh[gi];
        float gz = sd[gi + 100] + sbh[gi + 100];
        float gn = sd[gi + 200] + sbh[gi + 200];
        float xr = sd[gi + 300] + sbx[gi];
        float xz = sd[gi + 400] + sbx[gi + 100];
        float xn = sd[gi + 500] + sbx[gi + 200];
        float r = sigm_(xr + gr);
        float z = sigm_(xz + gz);
        float n = tanh_(xn + r * gn);
        hreg = (1.f - z) * n + z * hreg;
        sh[e][hs] = hreg;
    };
    auto dotsEnc = [&](int e, int buf) {
        v2f hv2[12], cv2[8];
        float h24;
        #pragma unroll
        for (int q = 0; q < 6; ++q) {
            float4 f = *(const float4*)&sh[e][28 * l + 4 * q];
            hv2[2 * q]     = v2f{f.x, f.y};
            hv2[2 * q + 1] = v2f{f.z, f.w};
        }
        h24 = sh[e][28 * l + 24];
        #pragma unroll
        for (int q = 0; q < 4; ++q) {
            float4 f = *(const float4*)&sctx[e][buf][16 * l + 4 * q];
            cv2[2 * q]     = v2f{f.x, f.y};
            cv2[2 * q + 1] = v2f{f.z, f.w};
        }
        float a0 = dotH_(w2[0], w1[0], hv2, h24);
        float a1 = dotH_(w2[1], w1[1], hv2, h24);
        float a2 = p2hh ? dotH_(w2[2], w1[2], hv2, h24) : dotC_(w2[2], cv2);
        float a3 = dotC_(w2[3], cv2);
        if (wl) {
            sdot[e][g] = a0;
            sdot[e][128 + g] = a1;
            sdot[e][256 + g] = a2;
            sdot[e][384 + g] = a3;
        }
        if (p4a) {
            float a4 = dotC_(w2[4], cv2);
            if (wl) sdot[e][512 + g] = a4;
        }
    };
    auto dotsDec = [&](int e) {
        v2f hv2[12];
        float h24;
        #pragma unroll
        for (int q = 0; q < 6; ++q) {
            float4 f = *(const float4*)&sh[e][28 * l + 4 * q];
            hv2[2 * q]     = v2f{f.x, f.y};
            hv2[2 * q + 1] = v2f{f.z, f.w};
        }
        h24 = sh[e][28 * l + 24];
        float a0 = dotH_(w2[0], w1[0], hv2, h24);
        float a1 = dotH_(w2[1], w1[1], hv2, h24);
        float a2 = dotH_(w2[2], w1[2], hv2, h24);
        float a3 = dotH_(w2[3], w1[3], hv2, h24);
        float a4 = dotH_(w2[4], w1[4], hv2, h24);
        if (wl) {
            sdot[e][g] = a0;
            sdot[e][128 + g] = a1;
            sdot[e][256 + g] = a2;
            sdot[e][384 + g] = a3;
            sdot[e][512 + g] = a4;
        }
        if (p5a) {
            float a5 = dotH_(w2[5], w1[5], hv2, h24);
            if (wl) sdot[e][640 + g] = a5;
        }
    };

    float4 pf;   // single prefetch reg; write-before-load each phase keeps lifetimes disjoint

    // ================ encoder: t = 0 .. len0-1 (len0 >= len1) ================
    for (int t = 0; t < len0; ++t) {
        // ---- phase A: dots(e0,t) || gate(e1,t-1) || prefetch ----
        if (isp) {
            if (t >= 1 && t < len1) *(float4*)&sctx[1][t & 1][4 * pi] = pf;  // e1 ctx for t
            if (t + 1 < len0) pf = pctx0[(t + 1) * 16 + pi];                 // e0 ctx for t+1
        }
        if (ge && tid < 200 && t >= 1 && t - 1 < len1) gate_(1);
        dotsEnc(0, t & 1);
        __syncthreads();
        // ---- phase B: dots(e1,t) || gate(e0,t) || prefetch ----
        if (isp) {
            if (t + 1 < len0) *(float4*)&sctx[0][(t + 1) & 1][4 * pi] = pf;  // e0 ctx for t+1
            if (t + 1 < len1) pf = pctx1[(t + 1) * 16 + pi];                 // e1 ctx for t+1
        }
        if (tid < 100) gate_(0);
        if (t < len1) dotsEnc(1, t & 1);   // block-uniform skip of finished element
        __syncthreads();
    }
    // drain: e1's final gate pending iff len1 == len0 (else it ran at phase A of t=len1)
    if (len1 == len0) {
        if (ge && tid < 200) gate_(1);
        __syncthreads();   // also separates old-sbx read from the rewrite below
    }

    // ---- switch input-path weights to decoder: Wd (+Wproj rows), bc -> bd ----
    {
        if (!p2hh) {
            const float* r2 = ws + WS_WD + (g - 44) * H_ + 25 * l;
            #pragma unroll
            for (int j = 0; j < 12; ++j) w2[2][j] = v2f{r2[2 * j], r2[2 * j + 1]};
            w1[2] = r2[24];
        }
        const float* r3 = ws + WS_WD + (84 + g) * H_ + 25 * l;
        #pragma unroll
        for (int j = 0; j < 12; ++j) w2[3][j] = v2f{r3[2 * j], r3[2 * j + 1]};
        w1[3] = r3[24];
        const float* r4 = p4a ? (ws + WS_WD + (212 + g) * H_ + 25 * l)
                              : (Wproj + (g - 88) * H_ + 25 * l);
        #pragma unroll
        for (int j = 0; j < 12; ++j) w2[4][j] = v2f{r4[2 * j], r4[2 * j + 1]};
        w1[4] = r4[24];
        if (p5a) {
            const float* r5 = Wproj + (40 + g) * H_ + 25 * l;
            #pragma unroll
            for (int j = 0; j < 12; ++j) w2[5][j] = v2f{r5[2 * j], r5[2 * j + 1]};
            w1[5] = r5[24];
        }
    }
    if (tid < H3) sbx[tid] = (ws + WS_BD)[tid];
    // safe: sbx first read in decoder phase B, after phase A's __syncthreads

    // ================ decoder: outputs t = 0..256 ================
    for (int t = 0; t <= T_; ++t) {
        // ---- phase A: dots(e0,t) || gate(e1,t-1) || out(e1,t-1) ----
        if (t >= 1) {
            if (ge && tid < 200) gate_(1);
            if (iso) oute1[(t - 1) * O_ + oo] = sdot[1][600 + oo] + bpr;
        }
        dotsDec(0);
        __syncthreads();
        // ---- phase B: dots(e1,t) || gate(e0,t) || out(e0,t) ----
        if (tid < 100 && t < T_) gate_(0);   // final e0 gate unneeded
        if (iso) oute0[t * O_ + oo] = sdot[0][600 + oo] + bpr;
        dotsDec(1);
        __syncthreads();
    }
    // drain: out(e1, T_)
    if (iso) oute1[T_ * O_ + oo] = sdot[1][600 + oo] + bpr;
}

extern "C" void kernel_launch(void* const* d_in, const int* in_sizes, int n_in,
                              void* d_out, int out_size, void* d_ws, size_t ws_size,
                              hipStream_t stream) {
    (void)in_sizes; (void)n_in; (void)out_size; (void)ws_size;
    const float* ctx  = (const float*)d_in[0];
    const int*   lens = (const int*)d_in[1];
    // d_in[2] = t_steps (256, hardcoded)
    const float* Wemb = (const float*)d_in[3];
    const float* bemb = (const float*)d_in[4];
    const float* Wih  = (const float*)d_in[5];
    const float* bih  = (const float*)d_in[6];
    const float* Whh  = (const float*)d_in[7];
    const float* bhh  = (const float*)d_in[8];
    const float* Wpr  = (const float*)d_in[9];
    const float* bpr  = (const float*)d_in[10];
    float* ws  = (float*)d_ws;
    float* out = (float*)d_out;

    prep1<<<H3, 64, 0, stream>>>(Wih, bih, Wemb, bemb, ws);
    prep2<<<H3, 128, 0, stream>>>(Wpr, bpr, ws);
    sortk<<<1, 512, 0, stream>>>(lens, (int*)(ws + WS_PERM));
    rnn9<<<256, 512, 0, stream>>>(ctx, lens, Whh, bhh, Wpr, bpr, ws, out);
}